// Round 3
// baseline (301.619 us; speedup 1.0000x reference)
//
#include <hip/hip_runtime.h>
#include <hip/hip_bf16.h>

#define B_ 32
#define S_ 2048
#define D_ 1024
#define H_ 512
#define M_ (B_*S_)   // 65536
#define BM 64
#define BN 512
#define BK 32

typedef __attribute__((ext_vector_type(8))) short short8;
typedef __attribute__((ext_vector_type(4))) float f32x4;

__device__ __forceinline__ unsigned short f2bf(float f){
  unsigned u = __builtin_bit_cast(unsigned, f);
  u += 0x7FFFu + ((u>>16)&1u);           // round-to-nearest-even
  return (unsigned short)(u>>16);
}

// XOR swizzle for a [rows][32] bf16 (=64B/row) LDS tile, 16B granularity.
__device__ __forceinline__ int swz(int row, int kshort){ // kshort multiple of 8
  return row*BK + (((kshort>>3) ^ row) & 3)*8 + (kshort & 7);
}

// ---------------- kernel W: W1 fp32 -> bf16, stored PRE-SWIZZLED -----------------
// element index = kt*(BN*BK) + swz(h, k%BK); global_load_lds writes LDS linearly
// so the swizzled image is reproduced exactly in Bs.
__global__ __launch_bounds__(256) void convw_kernel(
    const float* __restrict__ W1, unsigned short* __restrict__ W1s){
  int tid = blockIdx.x*256 + threadIdx.x;      // one thread per 8 elements
  int n = tid*8;
  int h = n >> 10;                             // row (D_=1024)
  int k = n & 1023;
  int kt = k >> 5;
  int kk = k & 31;
  float4 lo = *(const float4*)(W1 + n);
  float4 hi = *(const float4*)(W1 + n + 4);
  short8 r;
  r[0]=(short)f2bf(lo.x); r[1]=(short)f2bf(lo.y); r[2]=(short)f2bf(lo.z); r[3]=(short)f2bf(lo.w);
  r[4]=(short)f2bf(hi.x); r[5]=(short)f2bf(hi.y); r[6]=(short)f2bf(hi.z); r[7]=(short)f2bf(hi.w);
  *(short8*)&W1s[kt*(BN*BK) + swz(h, kk)] = r;
}

// ---------------- kernel 0: qbias[b,h] = W1_b[h] + W2_b[h] + query[b]·W2_w[h] ----
__global__ __launch_bounds__(256) void qbias_kernel(
    const float* __restrict__ hidden, const float* __restrict__ W2,
    const float* __restrict__ W1b, const float* __restrict__ W2b,
    float* __restrict__ qb){
  int b = blockIdx.x, h0 = blockIdx.y*64;
  int wave = threadIdx.x>>6, lane = threadIdx.x&63;
  const float* q = hidden + (size_t)(B_ + b)*D_;   // hidden[-1]
  for (int i=0;i<16;i++){
    int h = h0 + wave*16 + i;
    const float* w = W2 + (size_t)h*D_;
    float s = 0.f;
    #pragma unroll
    for (int it=0; it<4; ++it){
      int d = it*256 + lane*4;
      const float4 qq = *(const float4*)(q+d);
      const float4 ww = *(const float4*)(w+d);
      s += qq.x*ww.x + qq.y*ww.y + qq.z*ww.z + qq.w*ww.w;
    }
    #pragma unroll
    for (int off=1; off<64; off<<=1) s += __shfl_xor(s, off);
    if (lane==0) qb[b*H_ + h] = s + W1b[h] + W2b[h];
  }
}

// ---------------- kernel 1: fused score GEMM (full-H per block) ------------------
// 4 waves, wave-tile 64x128 (M x H), acc 4x8 fragments. No atomics.
__global__ __launch_bounds__(256) void score_gemm(
    const float* __restrict__ enc, const unsigned short* __restrict__ W1s,
    const float* __restrict__ qb, const float* __restrict__ Vw,
    float* __restrict__ score){
  const int bm = blockIdx.x;            // 0..1023 (m tile of 64)
  const int m0 = bm*BM;
  const int tid = threadIdx.x, lane = tid&63, wave = tid>>6;
  const int wn = wave*128;              // wave's h offset

  __shared__ __align__(16) unsigned short As[BM*BK];   //  4 KB
  __shared__ __align__(16) unsigned short Bs[BN*BK];   // 32 KB

  f32x4 acc[4][8];
  #pragma unroll
  for (int i=0;i<4;i++)
    #pragma unroll
    for (int j=0;j<8;j++)
      acc[i][j] = (f32x4)(0.f);

  const int arow = tid>>2, akc = (tid&3)*8;

  for (int kt=0; kt<D_/BK; ++kt){
    const int kk = kt*BK;
    float4 lo = *(const float4*)(enc + (size_t)(m0+arow)*D_ + kk + akc);
    float4 hi = *(const float4*)(enc + (size_t)(m0+arow)*D_ + kk + akc + 4);
    const unsigned short* bsrc = W1s + kt*(BN*BK);
    __syncthreads();                     // prev tile's ds_reads done
    #pragma unroll
    for (int i=0;i<8;i++){
      __builtin_amdgcn_global_load_lds(
        (const __attribute__((address_space(1))) unsigned int*)(bsrc + i*2048 + tid*8),
        (__attribute__((address_space(3))) unsigned int*)&Bs[i*2048 + tid*8],
        16, 0, 0);
    }
    short8 av;
    av[0]=(short)f2bf(lo.x); av[1]=(short)f2bf(lo.y); av[2]=(short)f2bf(lo.z); av[3]=(short)f2bf(lo.w);
    av[4]=(short)f2bf(hi.x); av[5]=(short)f2bf(hi.y); av[6]=(short)f2bf(hi.z); av[7]=(short)f2bf(hi.w);
    *(short8*)&As[swz(arow, akc)] = av;
    asm volatile("s_waitcnt vmcnt(0)" ::: "memory");
    __syncthreads();                     // tile visible
    const int kb = (lane>>4)*8;          // lane's k-offset (0/8/16/24)
    short8 af[4], bf[8];
    #pragma unroll
    for (int mi=0;mi<4;mi++){
      int row = mi*16 + (lane&15);
      af[mi] = *(const short8*)&As[swz(row, kb)];
    }
    #pragma unroll
    for (int ni=0;ni<8;ni++){
      int row = wn + ni*16 + (lane&15);
      bf[ni] = *(const short8*)&Bs[swz(row, kb)];
    }
    #pragma unroll
    for (int mi=0;mi<4;mi++)
      #pragma unroll
      for (int ni=0;ni<8;ni++)
        acc[mi][ni] = __builtin_amdgcn_mfma_f32_16x16x32_bf16(af[mi], bf[ni], acc[mi][ni], 0,0,0);
  }

  // ---- epilogue: tanh + V_w reduce; block owns full H so no atomics ------------
  const int bidx = m0 >> 11;            // batch (64 | 2048)
  float qv[8], vwv[8];
  #pragma unroll
  for (int ni=0;ni<8;ni++){
    int h = wn + ni*16 + (lane&15);
    qv[ni]  = qb[bidx*H_ + h];
    vwv[ni] = Vw[h];
  }
  __shared__ float psum[4][BM];
  #pragma unroll
  for (int mi=0;mi<4;mi++){
    #pragma unroll
    for (int r=0;r<4;r++){
      float s = 0.f;
      #pragma unroll
      for (int ni=0;ni<8;ni++) s += tanhf(acc[mi][ni][r] + qv[ni]) * vwv[ni];
      s += __shfl_xor(s,1); s += __shfl_xor(s,2);
      s += __shfl_xor(s,4); s += __shfl_xor(s,8);
      if ((lane&15)==0){
        int m = mi*16 + ((lane>>4)<<2) + r;
        psum[wave][m] = s;
      }
    }
  }
  __syncthreads();
  if (tid < BM)
    score[m0 + tid] = psum[0][tid] + psum[1][tid] + psum[2][tid] + psum[3][tid];
}

// ---------------- kernel 2: masked softmax over S --------------------------------
__global__ __launch_bounds__(256) void softmax_kernel(
    const float* __restrict__ score, const int* __restrict__ mask,
    float* __restrict__ attn){
  int b = blockIdx.x, tid = threadIdx.x;
  int wave = tid>>6, lane = tid&63;
  __shared__ float red[8];
  float v[8];
  float mx = -1e30f;
  #pragma unroll
  for (int i=0;i<8;i++){
    int s = tid + i*256;
    float sc = score[b*S_ + s];
    v[i] = (mask[b*S_ + s]==0) ? -1e9f : sc;
    mx = fmaxf(mx, v[i]);
  }
  #pragma unroll
  for (int off=1; off<64; off<<=1) mx = fmaxf(mx, __shfl_xor(mx, off));
  if (lane==0) red[wave] = mx;
  __syncthreads();
  mx = fmaxf(fmaxf(red[0],red[1]), fmaxf(red[2],red[3]));
  float sum = 0.f;
  #pragma unroll
  for (int i=0;i<8;i++){ v[i] = __expf(v[i]-mx); sum += v[i]; }
  #pragma unroll
  for (int off=1; off<64; off<<=1) sum += __shfl_xor(sum, off);
  if (lane==0) red[4+wave] = sum;
  __syncthreads();
  float inv = 1.f/(red[4]+red[5]+red[6]+red[7]);
  #pragma unroll
  for (int i=0;i<8;i++) attn[b*S_ + tid + i*256] = v[i]*inv;
}

// ---------------- kernel 3: context[b,d] = sum_s attn[b,s]*enc[b,s,d] ------------
__global__ __launch_bounds__(256) void context_kernel(
    const float* __restrict__ enc, const float* __restrict__ attn,
    float* __restrict__ ctx){
  int b = blockIdx.x, sc = blockIdx.y;        // 32 s-chunks of 64 rows
  int s0 = sc*64;
  int d4 = threadIdx.x*4;
  const float* ep = enc + ((size_t)b*S_ + s0)*D_ + d4;
  const float* ap = attn + b*S_ + s0;
  float4 acc = make_float4(0.f,0.f,0.f,0.f);
  #pragma unroll 4
  for (int i=0;i<64;i++){
    float w = ap[i];
    float4 e = *(const float4*)(ep + (size_t)i*D_);
    acc.x = fmaf(w, e.x, acc.x);
    acc.y = fmaf(w, e.y, acc.y);
    acc.z = fmaf(w, e.z, acc.z);
    acc.w = fmaf(w, e.w, acc.w);
  }
  float* o = ctx + b*D_ + d4;
  atomicAdd(o+0, acc.x); atomicAdd(o+1, acc.y);
  atomicAdd(o+2, acc.z); atomicAdd(o+3, acc.w);
}

extern "C" void kernel_launch(void* const* d_in, const int* in_sizes, int n_in,
                              void* d_out, int out_size, void* d_ws, size_t ws_size,
                              hipStream_t stream){
  const float* hidden = (const float*)d_in[0];
  const float* enc    = (const float*)d_in[1];
  const int*   mask   = (const int*)d_in[2];
  const float* W1w    = (const float*)d_in[3];
  const float* W1b    = (const float*)d_in[4];
  const float* W2w    = (const float*)d_in[5];
  const float* W2b    = (const float*)d_in[6];
  const float* Vw     = (const float*)d_in[7];
  // V_b (d_in[8]) provably cancels in softmax — unused.
  float* out = (float*)d_out;

  float* qb           = (float*)d_ws;                    // 64 KB
  float* score        = qb + B_*H_;                      // 256 KB
  unsigned short* W1s = (unsigned short*)(score + M_);   // 1 MB bf16 pre-swizzled

  hipMemsetAsync(out, 0, (size_t)B_*D_*sizeof(float), stream);

  convw_kernel  <<<H_*D_/8/256,     256, 0, stream>>>(W1w, W1s);
  qbias_kernel  <<<dim3(B_, H_/64), 256, 0, stream>>>(hidden, W2w, W1b, W2b, qb);
  score_gemm    <<<M_/BM,           256, 0, stream>>>(enc, W1s, qb, Vw, score);
  softmax_kernel<<<B_,              256, 0, stream>>>(score, mask, out + B_*D_);
  context_kernel<<<dim3(B_, 32),    256, 0, stream>>>(enc, out + B_*D_, out);
}

// Round 4
// 261.623 us; speedup vs baseline: 1.1529x; 1.1529x over previous
//
#include <hip/hip_runtime.h>
#include <hip/hip_bf16.h>

#define B_ 32
#define S_ 2048
#define D_ 1024
#define H_ 512
#define M_ (B_*S_)   // 65536
#define BM 128
#define BN 128
#define BK 64

typedef __attribute__((ext_vector_type(8))) short short8;
typedef __attribute__((ext_vector_type(4))) float f32x4;

__device__ __forceinline__ unsigned short f2bf(float f){
  unsigned u = __builtin_bit_cast(unsigned, f);
  u += 0x7FFFu + ((u>>16)&1u);           // round-to-nearest-even
  return (unsigned short)(u>>16);
}

// XOR swizzle for a [128][64] bf16 (=128B/row) LDS tile, 16B granularity.
// Reads (lanes 0-15 -> rows r..r+15, fixed k) hit 8 distinct banks x 2-way = free.
__device__ __forceinline__ int swz(int row, int kshort){
  return row*BK + ((kshort & 56) ^ ((row&7)<<3)) + (kshort & 7);
}

// ---------------- kernel W: W1 fp32 -> bf16, tile-major PRE-SWIZZLED -------------
// W1s[(bn*16+kt)*8192 + swz(row,kk)] = bf16(W1[bn*128+row][kt*64+kk])
// so score_gemm's linear global_load_lds reproduces the swizzled LDS image.
__global__ __launch_bounds__(256) void convw_kernel(
    const float* __restrict__ W1, unsigned short* __restrict__ W1s){
  int tid = blockIdx.x*256 + threadIdx.x;      // one thread per 8 elements
  int n = tid*8;
  int h = n >> 10;                             // row in [0,512)
  int k = n & 1023;
  int bn = h >> 7, row = h & 127;
  int kt = k >> 6, kk = k & 63;                // kk multiple of 8
  float4 lo = *(const float4*)(W1 + n);
  float4 hi = *(const float4*)(W1 + n + 4);
  short8 r;
  r[0]=(short)f2bf(lo.x); r[1]=(short)f2bf(lo.y); r[2]=(short)f2bf(lo.z); r[3]=(short)f2bf(lo.w);
  r[4]=(short)f2bf(hi.x); r[5]=(short)f2bf(hi.y); r[6]=(short)f2bf(hi.z); r[7]=(short)f2bf(hi.w);
  *(short8*)&W1s[(bn*16 + kt)*(BN*BK) + swz(row, kk)] = r;
}

// ---------------- kernel 0: qbias[b,h] = W1_b[h] + W2_b[h] + query[b]·W2_w[h] ----
__global__ __launch_bounds__(256) void qbias_kernel(
    const float* __restrict__ hidden, const float* __restrict__ W2,
    const float* __restrict__ W1b, const float* __restrict__ W2b,
    float* __restrict__ qb){
  int b = blockIdx.x, h0 = blockIdx.y*64;
  int wave = threadIdx.x>>6, lane = threadIdx.x&63;
  const float* q = hidden + (size_t)(B_ + b)*D_;   // hidden[-1]
  for (int i=0;i<16;i++){
    int h = h0 + wave*16 + i;
    const float* w = W2 + (size_t)h*D_;
    float s = 0.f;
    #pragma unroll
    for (int it=0; it<4; ++it){
      int d = it*256 + lane*4;
      const float4 qq = *(const float4*)(q+d);
      const float4 ww = *(const float4*)(w+d);
      s += qq.x*ww.x + qq.y*ww.y + qq.z*ww.z + qq.w*ww.w;
    }
    #pragma unroll
    for (int off=1; off<64; off<<=1) s += __shfl_xor(s, off);
    if (lane==0) qb[b*H_ + h] = s + W1b[h] + W2b[h];
  }
}

// ---------------- kernel 1: fused score GEMM (R1 structure + gload_lds B) --------
// grid (4 bn, 512 bm). Writes per-bn partial scores (no atomics).
__global__ __launch_bounds__(256) void score_gemm(
    const float* __restrict__ enc, const unsigned short* __restrict__ W1s,
    const float* __restrict__ qb, const float* __restrict__ Vw,
    float* __restrict__ score_p){
  const int bn = blockIdx.x;            // h tile (x fastest: 4 blocks share A tile)
  const int bm = blockIdx.y;
  const int m0 = bm*BM, h0 = bn*BN;
  const int tid = threadIdx.x, lane = tid&63, wave = tid>>6;
  const int wm = (wave>>1)*64, wn = (wave&1)*64;

  __shared__ __align__(16) unsigned short As[BM*BK];   // 16 KB
  __shared__ __align__(16) unsigned short Bs[BN*BK];   // 16 KB

  f32x4 acc[4][4];
  #pragma unroll
  for (int i=0;i<4;i++)
    #pragma unroll
    for (int j=0;j<4;j++)
      acc[i][j] = (f32x4)(0.f);

  for (int kt=0; kt<D_/BK; ++kt){
    const int kk = kt*BK;
    // ---- A: issue fp32 loads early (4 chunks of 8 floats per thread)
    float4 aLo[4], aHi[4];
    #pragma unroll
    for (int i=0;i<4;i++){
      int c = tid + i*256;
      int row = c>>3, kc = (c&7)*8;
      const float4* pa = (const float4*)(enc + (size_t)(m0+row)*D_ + kk + kc);
      aLo[i]=pa[0]; aHi[i]=pa[1];
    }
    __syncthreads();                     // prev tile's ds_reads done
    // ---- B: 16 KB via global_load_lds (pre-swizzled source, linear dest)
    const unsigned short* bsrc = W1s + (bn*16 + kt)*(BN*BK);
    #pragma unroll
    for (int i=0;i<4;i++){
      __builtin_amdgcn_global_load_lds(
        (const __attribute__((address_space(1))) unsigned int*)(bsrc + i*2048 + tid*8),
        (__attribute__((address_space(3))) unsigned int*)&Bs[i*2048 + tid*8],
        16, 0, 0);
    }
    // ---- A: convert + swizzled ds_write (overlaps with B loads in flight)
    #pragma unroll
    for (int i=0;i<4;i++){
      int c = tid + i*256;
      int row = c>>3, kc = (c&7)*8;
      short8 av;
      av[0]=(short)f2bf(aLo[i].x); av[1]=(short)f2bf(aLo[i].y);
      av[2]=(short)f2bf(aLo[i].z); av[3]=(short)f2bf(aLo[i].w);
      av[4]=(short)f2bf(aHi[i].x); av[5]=(short)f2bf(aHi[i].y);
      av[6]=(short)f2bf(aHi[i].z); av[7]=(short)f2bf(aHi[i].w);
      *(short8*)&As[swz(row, kc)] = av;
    }
    asm volatile("s_waitcnt vmcnt(0)" ::: "memory");
    __syncthreads();                     // tile visible
    // ---- compute: 2 k-halves x 4x4 fragments (32 MFMA/wave/K-step)
    #pragma unroll
    for (int kh=0; kh<2; ++kh){
      const int kb = kh*32 + (lane>>4)*8;
      short8 af[4], bf[4];
      #pragma unroll
      for (int mi=0;mi<4;mi++){
        int row = wm + mi*16 + (lane&15);
        af[mi] = *(const short8*)&As[swz(row, kb)];
      }
      #pragma unroll
      for (int ni=0;ni<4;ni++){
        int row = wn + ni*16 + (lane&15);
        bf[ni] = *(const short8*)&Bs[swz(row, kb)];
      }
      #pragma unroll
      for (int mi=0;mi<4;mi++)
        #pragma unroll
        for (int ni=0;ni<4;ni++)
          acc[mi][ni] = __builtin_amdgcn_mfma_f32_16x16x32_bf16(af[mi], bf[ni], acc[mi][ni], 0,0,0);
    }
  }

  // ---- epilogue: tanh + V_w reduce -> per-bn partial score (no atomics) --------
  const int bidx = m0 >> 11;            // batch (128 | 2048)
  float qv[4], vwv[4];
  #pragma unroll
  for (int ni=0;ni<4;ni++){
    int h = h0 + wn + ni*16 + (lane&15);
    qv[ni]  = qb[bidx*H_ + h];
    vwv[ni] = Vw[h];
  }
  __shared__ float psum[4][BM];
  #pragma unroll
  for (int mi=0;mi<4;mi++){
    #pragma unroll
    for (int r=0;r<4;r++){
      float s = 0.f;
      #pragma unroll
      for (int ni=0;ni<4;ni++) s += tanhf(acc[mi][ni][r] + qv[ni]) * vwv[ni];
      s += __shfl_xor(s,1); s += __shfl_xor(s,2);
      s += __shfl_xor(s,4); s += __shfl_xor(s,8);
      if ((lane&15)==0){
        int m = wm + mi*16 + ((lane>>4)<<2) + r;   // 0..127
        psum[wave][m] = s;
      }
    }
  }
  __syncthreads();
  if (tid < BM){
    int w0 = (tid>>6)*2;                 // rows 0-63 -> waves 0,1; 64-127 -> 2,3
    score_p[(size_t)bn*M_ + m0 + tid] = psum[w0][tid] + psum[w0+1][tid];
  }
}

// ---------------- kernel 2: masked softmax over S (sums 4 bn partials) -----------
__global__ __launch_bounds__(256) void softmax_kernel(
    const float* __restrict__ score_p, const int* __restrict__ mask,
    float* __restrict__ attn){
  int b = blockIdx.x, tid = threadIdx.x;
  int wave = tid>>6, lane = tid&63;
  __shared__ float red[8];
  float v[8];
  float mx = -1e30f;
  #pragma unroll
  for (int i=0;i<8;i++){
    int idx = b*S_ + tid + i*256;
    float sc = score_p[idx] + score_p[M_+idx] + score_p[2*M_+idx] + score_p[3*M_+idx];
    v[i] = (mask[idx]==0) ? -1e9f : sc;
    mx = fmaxf(mx, v[i]);
  }
  #pragma unroll
  for (int off=1; off<64; off<<=1) mx = fmaxf(mx, __shfl_xor(mx, off));
  if (lane==0) red[wave] = mx;
  __syncthreads();
  mx = fmaxf(fmaxf(red[0],red[1]), fmaxf(red[2],red[3]));
  float sum = 0.f;
  #pragma unroll
  for (int i=0;i<8;i++){ v[i] = __expf(v[i]-mx); sum += v[i]; }
  #pragma unroll
  for (int off=1; off<64; off<<=1) sum += __shfl_xor(sum, off);
  if (lane==0) red[4+wave] = sum;
  __syncthreads();
  float inv = 1.f/(red[4]+red[5]+red[6]+red[7]);
  #pragma unroll
  for (int i=0;i<8;i++) attn[b*S_ + tid + i*256] = v[i]*inv;
}

// ---------------- kernel 3: context[b,d] = sum_s attn[b,s]*enc[b,s,d] ------------
__global__ __launch_bounds__(256) void context_kernel(
    const float* __restrict__ enc, const float* __restrict__ attn,
    float* __restrict__ ctx){
  int b = blockIdx.x, sc = blockIdx.y;        // 32 s-chunks of 64 rows
  int s0 = sc*64;
  int d4 = threadIdx.x*4;
  const float* ep = enc + ((size_t)b*S_ + s0)*D_ + d4;
  const float* ap = attn + b*S_ + s0;
  float4 a0 = make_float4(0.f,0.f,0.f,0.f);
  float4 a1 = make_float4(0.f,0.f,0.f,0.f);
  #pragma unroll 4
  for (int i=0;i<64;i+=2){
    float w0 = ap[i], w1 = ap[i+1];
    float4 e0 = *(const float4*)(ep + (size_t)i*D_);
    float4 e1 = *(const float4*)(ep + (size_t)(i+1)*D_);
    a0.x = fmaf(w0, e0.x, a0.x); a0.y = fmaf(w0, e0.y, a0.y);
    a0.z = fmaf(w0, e0.z, a0.z); a0.w = fmaf(w0, e0.w, a0.w);
    a1.x = fmaf(w1, e1.x, a1.x); a1.y = fmaf(w1, e1.y, a1.y);
    a1.z = fmaf(w1, e1.z, a1.z); a1.w = fmaf(w1, e1.w, a1.w);
  }
  float* o = ctx + b*D_ + d4;
  atomicAdd(o+0, a0.x+a1.x); atomicAdd(o+1, a0.y+a1.y);
  atomicAdd(o+2, a0.z+a1.z); atomicAdd(o+3, a0.w+a1.w);
}

extern "C" void kernel_launch(void* const* d_in, const int* in_sizes, int n_in,
                              void* d_out, int out_size, void* d_ws, size_t ws_size,
                              hipStream_t stream){
  const float* hidden = (const float*)d_in[0];
  const float* enc    = (const float*)d_in[1];
  const int*   mask   = (const int*)d_in[2];
  const float* W1w    = (const float*)d_in[3];
  const float* W1b    = (const float*)d_in[4];
  const float* W2w    = (const float*)d_in[5];
  const float* W2b    = (const float*)d_in[6];
  const float* Vw     = (const float*)d_in[7];
  // V_b (d_in[8]) provably cancels in softmax — unused.
  float* out = (float*)d_out;

  float* qb           = (float*)d_ws;                    // 64 KB
  float* score_p      = qb + B_*H_;                      // 4*M_ f32 = 1 MB
  unsigned short* W1s = (unsigned short*)(score_p + 4*M_); // 1 MB bf16 pre-swizzled

  hipMemsetAsync(out, 0, (size_t)B_*D_*sizeof(float), stream);

  convw_kernel  <<<H_*D_/8/256,     256, 0, stream>>>(W1w, W1s);
  qbias_kernel  <<<dim3(B_, H_/64), 256, 0, stream>>>(hidden, W2w, W1b, W2b, qb);
  score_gemm    <<<dim3(4, M_/BM),  256, 0, stream>>>(enc, W1s, qb, Vw, score_p);
  softmax_kernel<<<B_,              256, 0, stream>>>(score_p, mask, out + B_*D_);
  context_kernel<<<dim3(B_, 32),    256, 0, stream>>>(enc, out + B_*D_, out);
}

// Round 5
// 190.308 us; speedup vs baseline: 1.5849x; 1.3747x over previous
//
#include <hip/hip_runtime.h>
#include <hip/hip_bf16.h>

#define B_ 32
#define S_ 2048
#define D_ 1024
#define H_ 512
#define M_ (B_*S_)   // 65536
#define BM 128
#define BN 128
#define BK 64

typedef __attribute__((ext_vector_type(8))) short short8;
typedef __attribute__((ext_vector_type(4))) float f32x4;

__device__ __forceinline__ unsigned short f2bf(float f){
  unsigned u = __builtin_bit_cast(unsigned, f);
  u += 0x7FFFu + ((u>>16)&1u);           // round-to-nearest-even
  return (unsigned short)(u>>16);
}

// XOR swizzle for a [128][64] bf16 (=128B/row) LDS tile, 16B granularity.
// Measured 0 bank conflicts (R4).
__device__ __forceinline__ int swz(int row, int kshort){
  return row*BK + ((kshort & 56) ^ ((row&7)<<3)) + (kshort & 7);
}

// ---------------- kernel W: W1 fp32 -> bf16, tile-major PRE-SWIZZLED -------------
__global__ __launch_bounds__(256) void convw_kernel(
    const float* __restrict__ W1, unsigned short* __restrict__ W1s){
  int tid = blockIdx.x*256 + threadIdx.x;      // one thread per 8 elements
  int n = tid*8;
  int h = n >> 10;                             // row in [0,512)
  int k = n & 1023;
  int bn = h >> 7, row = h & 127;
  int kt = k >> 6, kk = k & 63;
  float4 lo = *(const float4*)(W1 + n);
  float4 hi = *(const float4*)(W1 + n + 4);
  short8 r;
  r[0]=(short)f2bf(lo.x); r[1]=(short)f2bf(lo.y); r[2]=(short)f2bf(lo.z); r[3]=(short)f2bf(lo.w);
  r[4]=(short)f2bf(hi.x); r[5]=(short)f2bf(hi.y); r[6]=(short)f2bf(hi.z); r[7]=(short)f2bf(hi.w);
  *(short8*)&W1s[(bn*16 + kt)*(BN*BK) + swz(row, kk)] = r;
}

// ---------------- kernel 0: qbias[b,h] = W1_b[h] + W2_b[h] + query[b]·W2_w[h] ----
__global__ __launch_bounds__(256) void qbias_kernel(
    const float* __restrict__ hidden, const float* __restrict__ W2,
    const float* __restrict__ W1b, const float* __restrict__ W2b,
    float* __restrict__ qb){
  int b = blockIdx.x, h0 = blockIdx.y*64;
  int wave = threadIdx.x>>6, lane = threadIdx.x&63;
  const float* q = hidden + (size_t)(B_ + b)*D_;   // hidden[-1]
  for (int i=0;i<16;i++){
    int h = h0 + wave*16 + i;
    const float* w = W2 + (size_t)h*D_;
    float s = 0.f;
    #pragma unroll
    for (int it=0; it<4; ++it){
      int d = it*256 + lane*4;
      const float4 qq = *(const float4*)(q+d);
      const float4 ww = *(const float4*)(w+d);
      s += qq.x*ww.x + qq.y*ww.y + qq.z*ww.z + qq.w*ww.w;
    }
    #pragma unroll
    for (int off=1; off<64; off<<=1) s += __shfl_xor(s, off);
    if (lane==0) qb[b*H_ + h] = s + W1b[h] + W2b[h];
  }
}

// ---------------- kernel 1: fused score GEMM -------------------------------------
// XCD-aware 1-D grid: 4 same-bm blocks land on the SAME XCD (A shared via L2).
// Counted-vmcnt pipeline: A(kt+1) reg-prefetch stays in flight across barrier.
__global__ __launch_bounds__(256, 2) void score_gemm(
    const float* __restrict__ enc, const unsigned short* __restrict__ W1s,
    const float* __restrict__ qb, const float* __restrict__ Vw,
    float* __restrict__ score_p){
  const int id  = blockIdx.x;
  const int xcd = id & 7;
  const int j   = id >> 3;
  const int bm  = xcd*64 + (j >> 2);    // 0..511
  const int bn  = j & 3;                // 0..3
  const int m0 = bm*BM, h0 = bn*BN;
  const int tid = threadIdx.x, lane = tid&63, wave = tid>>6;
  const int wm = (wave>>1)*64, wn = (wave&1)*64;

  __shared__ __align__(16) unsigned short As[BM*BK];   // 16 KB
  __shared__ __align__(16) unsigned short Bs[BN*BK];   // 16 KB

  f32x4 acc[4][4];
  #pragma unroll
  for (int i=0;i<4;i++)
    #pragma unroll
    for (int j2=0;j2<4;j2++)
      acc[i][j2] = (f32x4)(0.f);

  const int arow = tid>>3, akc = (tid&7)*8;   // within-chunk: c=tid+i*256 -> row=c>>3

  // prologue: A(0) into regs
  float4 aLo[4], aHi[4];
  #pragma unroll
  for (int i=0;i<4;i++){
    int c = tid + i*256;
    int row = c>>3, kc = (c&7)*8;
    const float4* pa = (const float4*)(enc + (size_t)(m0+row)*D_ + kc);
    aLo[i]=pa[0]; aHi[i]=pa[1];
  }

  for (int kt=0; kt<16; ++kt){
    __builtin_amdgcn_s_barrier();            // all waves done reading prev tile
    __builtin_amdgcn_sched_barrier(0);
    // ---- B: 16 KB via global_load_lds (pre-swizzled source, linear dest)
    const unsigned short* bsrc = W1s + (bn*16 + kt)*(BN*BK);
    #pragma unroll
    for (int i=0;i<4;i++){
      __builtin_amdgcn_global_load_lds(
        (const __attribute__((address_space(1))) unsigned int*)(bsrc + i*2048 + tid*8),
        (__attribute__((address_space(3))) unsigned int*)&Bs[i*2048 + tid*8],
        16, 0, 0);
    }
    __builtin_amdgcn_sched_barrier(0);       // pin: B glds issued before A prefetch
    // ---- A: convert kt regs -> swizzled LDS (compiler auto-waits A(kt) vmcnt)
    #pragma unroll
    for (int i=0;i<4;i++){
      int c = tid + i*256;
      int row = c>>3, kc = (c&7)*8;
      short8 av;
      av[0]=(short)f2bf(aLo[i].x); av[1]=(short)f2bf(aLo[i].y);
      av[2]=(short)f2bf(aLo[i].z); av[3]=(short)f2bf(aLo[i].w);
      av[4]=(short)f2bf(aHi[i].x); av[5]=(short)f2bf(aHi[i].y);
      av[6]=(short)f2bf(aHi[i].z); av[7]=(short)f2bf(aHi[i].w);
      *(short8*)&As[swz(row, kc)] = av;
    }
    // ---- A: prefetch kt+1 (stays in flight across the barrier)
    if (kt < 15){
      const int kk1 = (kt+1)*BK;
      #pragma unroll
      for (int i=0;i<4;i++){
        int c = tid + i*256;
        int row = c>>3, kc = (c&7)*8;
        const float4* pa = (const float4*)(enc + (size_t)(m0+row)*D_ + kk1 + kc);
        aLo[i]=pa[0]; aHi[i]=pa[1];
      }
      __builtin_amdgcn_sched_barrier(0);
      asm volatile("s_waitcnt vmcnt(8) lgkmcnt(0)" ::: "memory"); // drain B only
    } else {
      __builtin_amdgcn_sched_barrier(0);
      asm volatile("s_waitcnt vmcnt(0) lgkmcnt(0)" ::: "memory");
    }
    __builtin_amdgcn_s_barrier();            // tile visible
    __builtin_amdgcn_sched_barrier(0);
    // ---- compute: 2 k-halves x 4x4 fragments (32 MFMA/wave/K-step)
    #pragma unroll
    for (int kh=0; kh<2; ++kh){
      const int kb = kh*32 + (lane>>4)*8;
      short8 af[4], bf[4];
      #pragma unroll
      for (int mi=0;mi<4;mi++){
        int row = wm + mi*16 + (lane&15);
        af[mi] = *(const short8*)&As[swz(row, kb)];
      }
      #pragma unroll
      for (int ni=0;ni<4;ni++){
        int row = wn + ni*16 + (lane&15);
        bf[ni] = *(const short8*)&Bs[swz(row, kb)];
      }
      #pragma unroll
      for (int mi=0;mi<4;mi++)
        #pragma unroll
        for (int ni=0;ni<4;ni++)
          acc[mi][ni] = __builtin_amdgcn_mfma_f32_16x16x32_bf16(af[mi], bf[ni], acc[mi][ni], 0,0,0);
    }
  }

  // ---- epilogue: tanh + V_w reduce -> per-bn partial score (no atomics) --------
  const int bidx = m0 >> 11;            // batch (128 | 2048)
  float qv[4], vwv[4];
  #pragma unroll
  for (int ni=0;ni<4;ni++){
    int h = h0 + wn + ni*16 + (lane&15);
    qv[ni]  = qb[bidx*H_ + h];
    vwv[ni] = Vw[h];
  }
  __shared__ float psum[4][BM];
  #pragma unroll
  for (int mi=0;mi<4;mi++){
    #pragma unroll
    for (int r=0;r<4;r++){
      float s = 0.f;
      #pragma unroll
      for (int ni=0;ni<4;ni++) s += tanhf(acc[mi][ni][r] + qv[ni]) * vwv[ni];
      s += __shfl_xor(s,1); s += __shfl_xor(s,2);
      s += __shfl_xor(s,4); s += __shfl_xor(s,8);
      if ((lane&15)==0){
        int m = wm + mi*16 + ((lane>>4)<<2) + r;   // 0..127
        psum[wave][m] = s;
      }
    }
  }
  __syncthreads();
  if (tid < BM){
    int w0 = (tid>>6)*2;
    score_p[(size_t)bn*M_ + m0 + tid] = psum[w0][tid] + psum[w0+1][tid];
  }
}

// ---------------- kernel 2: masked softmax over S (sums 4 bn partials) -----------
__global__ __launch_bounds__(256) void softmax_kernel(
    const float* __restrict__ score_p, const int* __restrict__ mask,
    float* __restrict__ attn){
  int b = blockIdx.x, tid = threadIdx.x;
  int wave = tid>>6, lane = tid&63;
  __shared__ float red[8];
  float v[8];
  float mx = -1e30f;
  #pragma unroll
  for (int i=0;i<8;i++){
    int idx = b*S_ + tid + i*256;
    float sc = score_p[idx] + score_p[M_+idx] + score_p[2*M_+idx] + score_p[3*M_+idx];
    v[i] = (mask[idx]==0) ? -1e9f : sc;
    mx = fmaxf(mx, v[i]);
  }
  #pragma unroll
  for (int off=1; off<64; off<<=1) mx = fmaxf(mx, __shfl_xor(mx, off));
  if (lane==0) red[wave] = mx;
  __syncthreads();
  mx = fmaxf(fmaxf(red[0],red[1]), fmaxf(red[2],red[3]));
  float sum = 0.f;
  #pragma unroll
  for (int i=0;i<8;i++){ v[i] = __expf(v[i]-mx); sum += v[i]; }
  #pragma unroll
  for (int off=1; off<64; off<<=1) sum += __shfl_xor(sum, off);
  if (lane==0) red[4+wave] = sum;
  __syncthreads();
  float inv = 1.f/(red[4]+red[5]+red[6]+red[7]);
  #pragma unroll
  for (int i=0;i<8;i++) attn[b*S_ + tid + i*256] = v[i]*inv;
}

// ---------------- kernel 3: context[b,d] = sum_s attn[b,s]*enc[b,s,d] ------------
__global__ __launch_bounds__(256) void context_kernel(
    const float* __restrict__ enc, const float* __restrict__ attn,
    float* __restrict__ ctx){
  int b = blockIdx.x, sc = blockIdx.y;        // 32 s-chunks of 64 rows
  int s0 = sc*64;
  int d4 = threadIdx.x*4;
  const float* ep = enc + ((size_t)b*S_ + s0)*D_ + d4;
  const float* ap = attn + b*S_ + s0;
  float4 a0 = make_float4(0.f,0.f,0.f,0.f);
  float4 a1 = make_float4(0.f,0.f,0.f,0.f);
  #pragma unroll 4
  for (int i=0;i<64;i+=2){
    float w0 = ap[i], w1 = ap[i+1];
    float4 e0 = *(const float4*)(ep + (size_t)i*D_);
    float4 e1 = *(const float4*)(ep + (size_t)(i+1)*D_);
    a0.x = fmaf(w0, e0.x, a0.x); a0.y = fmaf(w0, e0.y, a0.y);
    a0.z = fmaf(w0, e0.z, a0.z); a0.w = fmaf(w0, e0.w, a0.w);
    a1.x = fmaf(w1, e1.x, a1.x); a1.y = fmaf(w1, e1.y, a1.y);
    a1.z = fmaf(w1, e1.z, a1.z); a1.w = fmaf(w1, e1.w, a1.w);
  }
  float* o = ctx + b*D_ + d4;
  atomicAdd(o+0, a0.x+a1.x); atomicAdd(o+1, a0.y+a1.y);
  atomicAdd(o+2, a0.z+a1.z); atomicAdd(o+3, a0.w+a1.w);
}

extern "C" void kernel_launch(void* const* d_in, const int* in_sizes, int n_in,
                              void* d_out, int out_size, void* d_ws, size_t ws_size,
                              hipStream_t stream){
  const float* hidden = (const float*)d_in[0];
  const float* enc    = (const float*)d_in[1];
  const int*   mask   = (const int*)d_in[2];
  const float* W1w    = (const float*)d_in[3];
  const float* W1b    = (const float*)d_in[4];
  const float* W2w    = (const float*)d_in[5];
  const float* W2b    = (const float*)d_in[6];
  const float* Vw     = (const float*)d_in[7];
  // V_b (d_in[8]) provably cancels in softmax — unused.
  float* out = (float*)d_out;

  float* qb           = (float*)d_ws;                      // 64 KB
  float* score_p      = qb + B_*H_;                        // 4*M_ f32 = 1 MB
  unsigned short* W1s = (unsigned short*)(score_p + 4*M_); // 1 MB bf16 pre-swizzled

  hipMemsetAsync(out, 0, (size_t)B_*D_*sizeof(float), stream);

  convw_kernel  <<<H_*D_/8/256,     256, 0, stream>>>(W1w, W1s);
  qbias_kernel  <<<dim3(B_, H_/64), 256, 0, stream>>>(hidden, W2w, W1b, W2b, qb);
  score_gemm    <<<4*(M_/BM),       256, 0, stream>>>(enc, W1s, qb, Vw, score_p);
  softmax_kernel<<<B_,              256, 0, stream>>>(score_p, mask, out + B_*D_);
  context_kernel<<<dim3(B_, 32),    256, 0, stream>>>(enc, out + B_*D_, out);
}